// Round 12
// baseline (1714.568 us; speedup 1.0000x reference)
//
#include <hip/hip_runtime.h>
#include <cstdint>
#include <cstddef>

// Problem constants
#define T_  256
#define S_  128
#define B_  32
#define H_  1024
#define NH_ 16
#define D_  64
#define F_  4096
#define TB_ (T_*B_)   // 8192
#define SB_ (S_*B_)   // 4096

typedef unsigned short u16;
typedef unsigned int   u32;
typedef unsigned long long u64;
typedef __attribute__((ext_vector_type(8))) short s16x8;   // 8 bf16 (4 VGPRs)
typedef __attribute__((ext_vector_type(4))) float f32x4;
typedef __attribute__((ext_vector_type(4))) u32  u32x4;

static __device__ __forceinline__ float b2f(u16 u) {
  union { u32 i; float f; } cv; cv.i = ((u32)u) << 16; return cv.f;
}
static __device__ __forceinline__ u16 f2b(float f) {
  union { float f; u32 i; } cv; cv.f = f;
  u32 u = cv.i;
  u32 r = (u + 0x7fffu + ((u >> 16) & 1u)) >> 16;   // RNE
  return (u16)r;
}
static __device__ __forceinline__ float sigm(float x) {
  return 1.0f / (1.0f + __expf(-x));
}
static __device__ __forceinline__ float tanh_fast(float x) {
  float e2 = __expf(2.0f * x);
  return 1.0f - 2.0f / (e2 + 1.0f);
}

// async global->LDS DMA, 16B per lane
typedef const __attribute__((address_space(1))) void* gvoidp;
typedef __attribute__((address_space(3))) void* lvoidp;
static __device__ __forceinline__ void gl_lds16(const void* g, void* l) {
  __builtin_amdgcn_global_load_lds((gvoidp)g, (lvoidp)l, 16, 0, 0);
}

// ================= fused preprocessing (v13 version + gxs zero) =============
static __device__ __forceinline__ void cast_task(const float* __restrict__ in,
                                                 u16* __restrict__ out, int lb, int tid) {
  int i = lb * 256 + tid;
  float4 v = reinterpret_cast<const float4*>(in)[i];
  ushort4 o;
  o.x = f2b(v.x); o.y = f2b(v.y); o.z = f2b(v.z); o.w = f2b(v.w);
  reinterpret_cast<ushort4*>(out)[i] = o;
}

static __device__ __forceinline__ void tr32(const float* __restrict__ in,
                                            u16* __restrict__ out,
                                            int R, int C, int lin, int tid,
                                            float tile[32][33]) {
  const int gx = C >> 5;
  const int bx = lin % gx, by = lin / gx;
  const int c0 = bx << 5, r0 = by << 5;
  const int tx = tid & 31, ty = tid >> 5;   // ty 0..7
  #pragma unroll
  for (int k = 0; k < 32; k += 8)
    tile[ty + k][tx] = in[(size_t)(r0 + ty + k) * C + c0 + tx];
  __syncthreads();
  #pragma unroll
  for (int k = 0; k < 32; k += 8)
    out[(size_t)(c0 + ty + k) * R + r0 + tx] = f2b(tile[tx][ty + k]);
}

// block ranges (compile-time)
#define NB_SENT 1
#define NB_CX   8192
#define NB_CM   4096
#define NB_TSQ  1024
#define NB_TW1  4096
#define NB_TW2  4096
#define NB_TGX  8192
#define NB_TWH  4096
#define NB_PREP (NB_SENT + NB_CX + NB_CM + 4*NB_TSQ + NB_TW1 + NB_TW2 + NB_TGX + NB_TWH)

__global__ __launch_bounds__(256) void prep_all(
    const float* __restrict__ x, const float* __restrict__ mem,
    const float* __restrict__ Wq, const float* __restrict__ Wk,
    const float* __restrict__ Wv, const float* __restrict__ Wo,
    const float* __restrict__ W1, const float* __restrict__ W2,
    const float* __restrict__ Wg,
    u16* __restrict__ xb, u16* __restrict__ memb,
    u16* __restrict__ WqT, u16* __restrict__ WkT, u16* __restrict__ WvT,
    u16* __restrict__ WoT, u16* __restrict__ W1T, u16* __restrict__ W2T,
    u16* __restrict__ WgxT, u16* __restrict__ WhT, u32* __restrict__ sent,
    u32* __restrict__ gxs)
{
  __shared__ float tile[32][33];
  int b = blockIdx.x;
  const int tid = threadIdx.x;
  if (b < NB_SENT) {
    sent[tid] = 0; sent[tid + 256] = 0;
    gxs[tid] = 0;  gxs[tid + 256] = 0;       // 512 gate-tile sentinels
    return;
  }
  b -= NB_SENT;
  if (b < NB_CX) { cast_task(x, xb, b, tid); return; }      b -= NB_CX;
  if (b < NB_CM) { cast_task(mem, memb, b, tid); return; }  b -= NB_CM;
  if (b < NB_TSQ) { tr32(Wq, WqT, H_, H_, b, tid, tile); return; }  b -= NB_TSQ;
  if (b < NB_TSQ) { tr32(Wk, WkT, H_, H_, b, tid, tile); return; }  b -= NB_TSQ;
  if (b < NB_TSQ) { tr32(Wv, WvT, H_, H_, b, tid, tile); return; }  b -= NB_TSQ;
  if (b < NB_TSQ) { tr32(Wo, WoT, H_, H_, b, tid, tile); return; }  b -= NB_TSQ;
  if (b < NB_TW1) { tr32(W1, W1T, H_, F_, b, tid, tile); return; }  b -= NB_TW1;
  if (b < NB_TW2) { tr32(W2, W2T, F_, H_, b, tid, tile); return; }  b -= NB_TW2;
  if (b < NB_TGX) { tr32(Wg, WgxT, 2 * H_, 4 * H_, b, tid, tile); return; } b -= NB_TGX;
  tr32(Wg + (size_t)(2 * H_) * (4 * H_), WhT, H_, 4 * H_, b, tid, tile);
}

// ================= GEMM 256x256 / BK=64, 4-phase counted-vmcnt schedule =====
#define SBAR      asm volatile("s_barrier" ::: "memory")
#define VMCNT4    asm volatile("s_waitcnt vmcnt(4)" ::: "memory")
#define VMCNT0    asm volatile("s_waitcnt vmcnt(0)" ::: "memory")

struct GJob {
  const u16* A; const u16* Bt; u16* Out; const float* bias;
  int Kdim; int ostride; int relu; int gridx; int nblk; float scale;
};
struct GBatch { GJob j[4]; int starts[4]; int njobs; };

// stage one [256][32] region (rows row0.., k = kt*64+kh*32..) into lds_region
static __device__ __forceinline__ void stage_region(
    const u16* __restrict__ src, int Kdim, int row0,
    int kt, int kh, char* lds_region, int tid) {
  const int w  = tid >> 6;
  const int r  = tid >> 2;                  // 0..127
  const int cs = (tid & 3) ^ ((tid >> 3) & 3);   // pre-swizzled source chunk
  const int kbase = kt * 64 + kh * 32 + cs * 8;
  gl_lds16(src + (size_t)(row0 + r) * Kdim + kbase,        lds_region + w * 1024);
  gl_lds16(src + (size_t)(row0 + 128 + r) * Kdim + kbase,  lds_region + 8192 + w * 1024);
}

static __device__ __forceinline__ s16x8 ldsf(const char* sm, int base, int row, int quad) {
  return *(const s16x8*)(sm + base + row * 64 + ((quad ^ ((row >> 1) & 3)) << 4));
}

// 4-phase compute core (prologue + K loop, no epilogue). Proven v13 schedule.
static __device__ __forceinline__ void gemm_compute(
    const GJob& J, int bm, int bn, char* sm, f32x4 (&acc)[8][4], int tid)
{
  const int wavei = tid >> 6, lane = tid & 63;
  const int quad = lane >> 4, l16 = lane & 15;
  const int wm = wavei >> 2, wn = wavei & 3;
  const int NT = J.Kdim >> 6;
  const int arow = wm * 128;
  const int brow = wn * 64;

  stage_region(J.A,  J.Kdim, bm, 0, 0, sm + 0,     tid);
  stage_region(J.Bt, J.Kdim, bn, 0, 0, sm + 32768, tid);
  stage_region(J.A,  J.Kdim, bm, 0, 1, sm + 16384, tid);
  stage_region(J.Bt, J.Kdim, bn, 0, 1, sm + 49152, tid);
  VMCNT4;
  SBAR;

  for (int kt = 0; kt < NT; kt++) {
    const int p = (kt & 1) << 16;
    const int q = p ^ 65536;
    const int Ab = p, Bb = p + 32768;
    const bool st = (kt + 1 < NT);
    s16x8 af[8], b0, b1;

    #pragma unroll
    for (int mi = 0; mi < 8; mi++)
      af[mi] = ldsf(sm, Ab, arow + mi * 16 + l16, quad);
    b0 = ldsf(sm, Bb, brow + l16, quad);
    b1 = ldsf(sm, Bb, brow + 16 + l16, quad);
    if (st) stage_region(J.A, J.Kdim, bm, kt + 1, 0, sm + q, tid);
    SBAR;
    __builtin_amdgcn_s_setprio(1);
    #pragma unroll
    for (int mi = 0; mi < 8; mi++) {
      acc[mi][0] = __builtin_amdgcn_mfma_f32_16x16x32_bf16(af[mi], b0, acc[mi][0], 0, 0, 0);
      acc[mi][1] = __builtin_amdgcn_mfma_f32_16x16x32_bf16(af[mi], b1, acc[mi][1], 0, 0, 0);
    }
    __builtin_amdgcn_s_setprio(0);
    SBAR;

    b0 = ldsf(sm, Bb, brow + 32 + l16, quad);
    b1 = ldsf(sm, Bb, brow + 48 + l16, quad);
    if (st) stage_region(J.Bt, J.Kdim, bn, kt + 1, 0, sm + q + 32768, tid);
    SBAR;
    __builtin_amdgcn_s_setprio(1);
    #pragma unroll
    for (int mi = 0; mi < 8; mi++) {
      acc[mi][2] = __builtin_amdgcn_mfma_f32_16x16x32_bf16(af[mi], b0, acc[mi][2], 0, 0, 0);
      acc[mi][3] = __builtin_amdgcn_mfma_f32_16x16x32_bf16(af[mi], b1, acc[mi][3], 0, 0, 0);
    }
    __builtin_amdgcn_s_setprio(0);
    if (st) { VMCNT4; } else { VMCNT0; }
    SBAR;

    const int Ab1 = Ab + 16384, Bb1 = Bb + 16384;
    #pragma unroll
    for (int mi = 0; mi < 8; mi++)
      af[mi] = ldsf(sm, Ab1, arow + mi * 16 + l16, quad);
    b0 = ldsf(sm, Bb1, brow + l16, quad);
    b1 = ldsf(sm, Bb1, brow + 16 + l16, quad);
    if (st) stage_region(J.A, J.Kdim, bm, kt + 1, 1, sm + q + 16384, tid);
    SBAR;
    __builtin_amdgcn_s_setprio(1);
    #pragma unroll
    for (int mi = 0; mi < 8; mi++) {
      acc[mi][0] = __builtin_amdgcn_mfma_f32_16x16x32_bf16(af[mi], b0, acc[mi][0], 0, 0, 0);
      acc[mi][1] = __builtin_amdgcn_mfma_f32_16x16x32_bf16(af[mi], b1, acc[mi][1], 0, 0, 0);
    }
    __builtin_amdgcn_s_setprio(0);
    SBAR;

    b0 = ldsf(sm, Bb1, brow + 32 + l16, quad);
    b1 = ldsf(sm, Bb1, brow + 48 + l16, quad);
    if (st) stage_region(J.Bt, J.Kdim, bn, kt + 1, 1, sm + q + 49152, tid);
    SBAR;
    __builtin_amdgcn_s_setprio(1);
    #pragma unroll
    for (int mi = 0; mi < 8; mi++) {
      acc[mi][2] = __builtin_amdgcn_mfma_f32_16x16x32_bf16(af[mi], b0, acc[mi][2], 0, 0, 0);
      acc[mi][3] = __builtin_amdgcn_mfma_f32_16x16x32_bf16(af[mi], b1, acc[mi][3], 0, 0, 0);
    }
    __builtin_amdgcn_s_setprio(0);
    if (st) { VMCNT4; }
    SBAR;
  }
}

__global__ __launch_bounds__(512, 2) void gemm256(GBatch gb)
{
  __shared__ __align__(16) u16 smem[65536];   // 128 KB
  char* sm = (char*)smem;
  const int bid = blockIdx.x;
  int ji = 0;
  #pragma unroll
  for (int t = 1; t < 4; t++)
    if (t < gb.njobs && bid >= gb.starts[t]) ji = t;
  const GJob J = gb.j[ji];
  const int lin = bid - gb.starts[ji];
  const int wg = (lin & 7) * (J.nblk >> 3) + (lin >> 3);   // bijective XCD swizzle
  const int bx = wg % J.gridx, by = wg / J.gridx;
  const int bm = by << 8, bn = bx << 8;
  const int tid = threadIdx.x;
  const int wavei = tid >> 6, lane = tid & 63;
  const int quad = lane >> 4, l16 = lane & 15;
  const int wm = wavei >> 2, wn = wavei & 3;

  f32x4 acc[8][4] = {};
  gemm_compute(J, bm, bn, sm, acc, tid);

  #pragma unroll
  for (int mi = 0; mi < 8; mi++) {
    #pragma unroll
    for (int nj = 0; nj < 4; nj++) {
      const int colo = bn + wn * 64 + nj * 16 + l16;
      const float bv = J.bias[colo];
      #pragma unroll
      for (int r = 0; r < 4; r++) {
        const int rowo = bm + wm * 128 + mi * 16 + quad * 4 + r;
        float vv = (acc[mi][nj][r] + bv) * J.scale;
        if (J.relu) vv = fmaxf(vv, 0.0f);
        J.Out[(size_t)rowo * J.ostride + colo] = f2b(vv);
      }
    }
  }
}

// ---------------- attention ----------------
__global__ __launch_bounds__(256) void attn_kernel(
    const u16* __restrict__ q, const u16* __restrict__ k, const u16* __restrict__ v,
    const float* __restrict__ src_bias, u16* __restrict__ ctx)
{
  __shared__ u16 ks[S_ * D_];
  __shared__ u16 vs[S_ * D_];
  const int b  = blockIdx.x >> 4;
  const int nh = blockIdx.x & 15;
  const int tid = threadIdx.x;

  for (int i = tid; i < (S_ * D_) / 8; i += 256) {
    int s = i >> 3, c = (i & 7) * 8;
    *(uint4*)&ks[s * D_ + c] = *(const uint4*)&k[((size_t)(s * B_ + b)) * H_ + nh * D_ + c];
    *(uint4*)&vs[s * D_ + c] = *(const uint4*)&v[((size_t)(s * B_ + b)) * H_ + nh * D_ + c];
  }
  __syncthreads();

  const int t = tid;
  float qf[D_];
  const u16* qp = &q[((size_t)(t * B_ + b)) * H_ + nh * D_];
  #pragma unroll
  for (int c8 = 0; c8 < D_; c8 += 8) {
    uint4 qv = *(const uint4*)&qp[c8];
    const u16* pu = (const u16*)&qv;
    #pragma unroll
    for (int j = 0; j < 8; j++) qf[c8 + j] = b2f(pu[j]);
  }
  const float* bias = src_bias + b * S_;

  float m = -1e30f, l = 0.0f;
  for (int s = 0; s < S_; s++) {
    float dot = 0.0f;
    #pragma unroll
    for (int d = 0; d < D_; d++) dot += qf[d] * b2f(ks[s * D_ + d]);
    dot += bias[s];
    float nm = fmaxf(m, dot);
    l = l * __expf(m - nm) + __expf(dot - nm);
    m = nm;
  }
  float of[D_] = {};
  const float inv = 1.0f / l;
  for (int s = 0; s < S_; s++) {
    float dot = 0.0f;
    #pragma unroll
    for (int d = 0; d < D_; d++) dot += qf[d] * b2f(ks[s * D_ + d]);
    dot += bias[s];
    float w = __expf(dot - m) * inv;
    #pragma unroll
    for (int d = 0; d < D_; d++) of[d] += w * b2f(vs[s * D_ + d]);
  }
  u16* op = &ctx[((size_t)(t * B_ + b)) * H_ + nh * D_];
  #pragma unroll
  for (int c8 = 0; c8 < D_; c8 += 8) {
    u16 tmp[8];
    #pragma unroll
    for (int j = 0; j < 8; j++) tmp[j] = f2b(of[c8 + j]);
    *(uint4*)&op[c8] = *(const uint4*)tmp;
  }
}

// ============ fused gate-GEMM + persistent LSTM (producer/consumer) =========
// Blocks 0..63: LSTM (512 thr; waves 4-7 mirror the fixed barrier sequence).
// Blocks 64..575: gate GEMM tiles, by-major order (row-block 0 first), with
// sc0/sc1 write-through epilogue -> vmcnt(0) -> barrier -> gxs[by][bx]=1
// (the proven v9 release pattern). LSTM polls gxs per row-block (every 8
// steps) and reads g_x with sc0/sc1 loads (g_x aliases h1 whose lines sit
// clean-stale in L2s from the ffn2 launch -> plain loads would be wrong),
// batch-issued and drained by the h-sentinel spin's vmcnt(0); sched_barrier
// guards against register-use hoisting (rule #18). No deadlock: only the 64
// LSTM blocks ever wait; gemm blocks never wait; 192 CUs always free.
#define WAIT0A asm volatile("s_waitcnt vmcnt(0)" ::: "memory")

#define ISSUE2(K) { \
  const u16* b0_ = hb + ((size_t)(wave * 16 + (K) * 2 + (quad >> 1))) * 512 + \
                   (quad & 1) * 8 + l16 * 16; \
  asm volatile("global_load_dwordx4 %0, %1, off sc0 sc1" : "=v"(ba[K][0]) : "v"(b0_) : "memory"); \
  asm volatile("global_load_dwordx4 %0, %1, off sc0 sc1" : "=v"(ba[K][1]) : "v"(b0_ + 256) : "memory"); }

#define DO_MFMA(A0,A1,KC)                                                           \
  { _Pragma("unroll") for (int g_ = 0; g_ < 3; g_++) {                              \
      s16x8 wf_ = *(const s16x8*)&Wl[wave * 12288 + ((g_ * 8 + (KC)) * 64 + lane) * 8]; \
      acc2[g_][0] = __builtin_amdgcn_mfma_f32_16x16x32_bf16(A0, wf_, acc2[g_][0], 0, 0, 0); \
      acc2[g_][1] = __builtin_amdgcn_mfma_f32_16x16x32_bf16(A1, wf_, acc2[g_][1], 0, 0, 0); } \
    acc2[3][0] = __builtin_amdgcn_mfma_f32_16x16x32_bf16(A0, wo[KC], acc2[3][0], 0, 0, 0);  \
    acc2[3][1] = __builtin_amdgcn_mfma_f32_16x16x32_bf16(A1, wo[KC], acc2[3][1], 0, 0, 0); }

#define CONSUME(K, NSTR) { \
  asm volatile("s_waitcnt vmcnt(" NSTR ")" ::: "memory"); \
  __builtin_amdgcn_sched_barrier(0); \
  DO_MFMA(ba[K][0], ba[K][1], K); }

#define PIDX(W,G,ROW,C) ((((W) * 4 + (G)) * 32 + (ROW)) * 17 + (C))

#define ISSUE_GX(TT) { \
  _Pragma("unroll") for (int ii_ = 0; ii_ < 2; ii_++) \
    _Pragma("unroll") for (int g_ = 0; g_ < 4; g_++) { \
      const u16* gp_ = g_x + ((size_t)((TT) * B_ + pb + ii_ * 16)) * (4 * H_) + g_ * H_ + col; \
      asm volatile("global_load_ushort %0, %1, off sc0 sc1" : "=v"(gq[ii_ * 4 + g_]) : "v"(gp_) : "memory"); } }

#define CVT_GX() { \
  _Pragma("unroll") for (int ii_ = 0; ii_ < 2; ii_++) \
    _Pragma("unroll") for (int g_ = 0; g_ < 4; g_++) \
      gxp[ii_][g_] = b2f((u16)gq[ii_ * 4 + g_]); }

#define POLLGXS(RB) { \
  const u32* sp_ = gxs + (RB) * 16 + (lane & 3) * 4 + (bk >> 4); \
  u32 sv_; \
  do { asm volatile("global_load_dword %0, %1, off sc0 sc1\n\ts_waitcnt vmcnt(0)" \
                    : "=v"(sv_) : "v"(sp_) : "memory"); } while (!__all(sv_ != 0)); }

__global__ __launch_bounds__(512, 1) void gate_lstm(
    GBatch gb, const u16* __restrict__ g_x, const u16* __restrict__ WhT,
    u16* __restrict__ hb16, u32* __restrict__ sent, u32* __restrict__ gxs,
    float* __restrict__ out)
{
  __shared__ __align__(16) char smem[133120];   // union: gemm 128KB / lstm 130KB
  const int tid = threadIdx.x;

  if (blockIdx.x >= 64) {
    // ---------------- gate GEMM tile (coherent epilogue) ----------------
    const GJob J = gb.j[0];
    const int lin = blockIdx.x - 64;
    const int bx = lin & 15, by = lin >> 4;     // by-major: row-block 0 first
    const int bm = by << 8, bn = bx << 8;
    const int wavei = tid >> 6, lane = tid & 63;
    const int quad = lane >> 4, l16 = lane & 15;
    const int wm = wavei >> 2, wn = wavei & 3;
    f32x4 acc[8][4] = {};
    gemm_compute(J, bm, bn, smem, acc, tid);
    #pragma unroll
    for (int mi = 0; mi < 8; mi++) {
      #pragma unroll
      for (int nj = 0; nj < 4; nj++) {
        const int colo = bn + wn * 64 + nj * 16 + l16;
        const float bv = J.bias[colo];
        #pragma unroll
        for (int r = 0; r < 4; r++) {
          const int rowo = bm + wm * 128 + mi * 16 + quad * 4 + r;
          u32 hv = f2b(acc[mi][nj][r] + bv);
          u16* op_ = J.Out + (size_t)rowo * J.ostride + colo;
          asm volatile("global_store_short %0, %1, off sc0 sc1" :: "v"(op_), "v"(hv) : "memory");
        }
      }
    }
    WAIT0A;                 // own write-through stores at coherence point
    __syncthreads();        // all 512 threads' stores done
    if (tid == 0)
      __hip_atomic_store(&gxs[by * 16 + bx], 1u, __ATOMIC_RELAXED, __HIP_MEMORY_SCOPE_AGENT);
    return;
  }

  // ---------------- LSTM block (v9 sync structure, 512 threads) ----------
  const int bk = blockIdx.x;
  const int wave = tid >> 6, lane = tid & 63;
  const int quad = lane >> 4, l16 = lane & 15;
  u16*   Wl = (u16*)smem;                    // [4][12288] u16 = 96 KB
  float* P  = (float*)(smem + 98304);        // [4][4][32][17] = 34.8 KB

  s16x8 wo[8];
  if (tid < 256) {
    for (int i = lane; i < 3 * 8 * 64; i += 64) {
      const int g  = (i >> 9) & 3;
      const int kc = (i >> 6) & 7;
      const int row = g * H_ + bk * 16 + (lane & 15);
      const int cw  = wave * 256 + kc * 32 + (lane >> 4) * 8;
      *(uint4*)&Wl[wave * 12288 + i * 8] = *(const uint4*)&WhT[(size_t)row * H_ + cw];
    }
    const int row = 3 * H_ + bk * 16 + (lane & 15);
    const int colb = wave * 256 + (lane >> 4) * 8;
    #pragma unroll
    for (int kc = 0; kc < 8; kc++)
      wo[kc] = *(const s16x8*)&WhT[(size_t)row * H_ + colb + kc * 32];
  }
  __syncthreads();

  const int pb = tid >> 4, pc = tid & 15;
  const int col = bk * 16 + pc;
  float creg[2] = {0.0f, 0.0f};
  float gxp[2][4];
  u32 gq[8];
  s16x8 ba[8][2];

  if (tid < 256) {                           // initial g_x for t=0 (rb 0)
    POLLGXS(0);
    ISSUE_GX(0);
    WAIT0A;
    __builtin_amdgcn_sched_barrier(0);
    CVT_GX();
  }

  for (int t = 0; t < T_; t++) {
    if (tid < 256 && t > 0) {
      const u32 st = (u32)t;
      const u16* hb = hb16 + ((t & 1) ^ 1) * 32768;
      // acquire: 64 producer-wave sentinels (contains vmcnt(0) -> drains gq)
      { const u32* sp = sent + ((size_t)(((t & 1) ^ 1) * 256 + wave * 64 + lane));
        u32 sv;
        do {
          asm volatile("global_load_dword %0, %1, off sc0 sc1\n\ts_waitcnt vmcnt(0)"
                       : "=v"(sv) : "v"(sp) : "memory");
        } while (!__all(sv == st)); }
      __builtin_amdgcn_sched_barrier(0);
      CVT_GX();                              // g_x for this t (issued at t-1)

      f32x4 acc2[4][2] = {};
      ISSUE2(0) ISSUE2(1) ISSUE2(2) ISSUE2(3)
      ISSUE2(4) ISSUE2(5) ISSUE2(6) ISSUE2(7)
      CONSUME(0, "14") CONSUME(1, "12") CONSUME(2, "10") CONSUME(3, "8")
      CONSUME(4, "6")  CONSUME(5, "4")  CONSUME(6, "2")  CONSUME(7, "0")

      #pragma unroll
      for (int g = 0; g < 4; g++)
        #pragma unroll
        for (int mt = 0; mt < 2; mt++)
          #pragma unroll
          for (int r = 0; r < 4; r++)
            P[PIDX(wave, g, mt * 16 + quad * 4 + r, l16)] = acc2[g][mt][r];
    }
    __syncthreads();

    float gs[2][4];
    if (tid < 256) {
      #pragma unroll
      for (int ii = 0; ii < 2; ii++) {
        const int b_ = pb + ii * 16;
        #pragma unroll
        for (int g = 0; g < 4; g++) {
          float s = gxp[ii][g];
          if (t > 0) s += P[PIDX(0, g, b_, pc)] + P[PIDX(1, g, b_, pc)]
                        + P[PIDX(2, g, b_, pc)] + P[PIDX(3, g, b_, pc)];
          gs[ii][g] = s;
        }
      }
    }
    __syncthreads();   // P consumed; next step may overwrite

    if (tid < 256) {
      float hn[2], cn[2];
      #pragma unroll
      for (int ii = 0; ii < 2; ii++) {
        const float iv = sigm(gs[ii][0]);
        const float jv = tanh_fast(gs[ii][1]);
        const float fv = sigm(gs[ii][2]);
        const float ov = sigm(gs[ii][3]);
        cn[ii] = fv * creg[ii] + iv * jv;
        hn[ii] = ov * cn[ii];
        creg[ii] = cn[ii];
      }

      // release: bf16 data stores (agent) -> own-wave drain -> sentinel
      {
        u32 lo0 = f2b(hn[0]), lo1 = f2b(hn[1]);
        u32 hi0 = __shfl_down(lo0, 1), hi1 = __shfl_down(lo1, 1);
        if ((pc & 1) == 0) {
          u32* hw32 = (u32*)(hb16 + (t & 1) * 32768);
          u32 dw0 = lo0 | (hi0 << 16);
          u32 dw1 = lo1 | (hi1 << 16);
          __hip_atomic_store(&hw32[(size_t)bk * 256 + pb * 8 + (pc >> 1)], dw0,
                             __ATOMIC_RELAXED, __HIP_MEMORY_SCOPE_AGENT);
          __hip_atomic_store(&hw32[(size_t)bk * 256 + (pb + 16) * 8 + (pc >> 1)], dw1,
                             __ATOMIC_RELAXED, __HIP_MEMORY_SCOPE_AGENT);
        }
        WAIT0A;
        if (lane == 0)
          __hip_atomic_store(&sent[(size_t)(t & 1) * 256 + bk * 4 + wave], (u32)(t + 1),
                             __ATOMIC_RELAXED, __HIP_MEMORY_SCOPE_AGENT);
      }

      // deferred: fp32 outputs + next g_x prefetch (poll rb on transitions)
      #pragma unroll
      for (int ii = 0; ii < 2; ii++) {
        const int b_ = pb + ii * 16;
        out[(size_t)t * (B_ * H_) + b_ * H_ + col] = hn[ii];
        if (t == T_ - 1) {
          out[(size_t)T_ * B_ * H_ + b_ * H_ + col] = cn[ii];              // c_f
          out[(size_t)T_ * B_ * H_ + B_ * H_ + b_ * H_ + col] = hn[ii];    // h_f
        }
      }
      if (t < T_ - 1) {
        if (((t + 1) & 7) == 0) POLLGXS((t + 1) >> 3);
        ISSUE_GX(t + 1);
      }
    }
  }
}

extern "C" void kernel_launch(void* const* d_in, const int* in_sizes, int n_in,
                              void* d_out, int out_size, void* d_ws, size_t ws_size,
                              hipStream_t stream)
{
  const float* x        = (const float*)d_in[0];
  const float* src_bias = (const float*)d_in[1];
  const float* mem      = (const float*)d_in[3];
  const float* Wq = (const float*)d_in[4];  const float* bq = (const float*)d_in[5];
  const float* Wk = (const float*)d_in[6];  const float* bk = (const float*)d_in[7];
  const float* Wv = (const float*)d_in[8];  const float* bv = (const float*)d_in[9];
  const float* Wo = (const float*)d_in[10]; const float* bo = (const float*)d_in[11];
  const float* W1 = (const float*)d_in[12]; const float* b1f = (const float*)d_in[13];
  const float* W2 = (const float*)d_in[14]; const float* b2f_ = (const float*)d_in[15];
  const float* Wg = (const float*)d_in[16]; const float* bg = (const float*)d_in[17];
  float* out = (float*)d_out;

  char* p = (char*)d_ws;
  u16* xb   = (u16*)p; p += (size_t)TB_ * H_ * 2;
  u16* memb = (u16*)p; p += (size_t)SB_ * H_ * 2;
  u16* WqT  = (u16*)p; p += (size_t)H_ * H_ * 2;
  u16* WkT  = (u16*)p; p += (size_t)H_ * H_ * 2;
  u16* WvT  = (u16*)p; p += (size_t)H_ * H_ * 2;
  u16* WoT  = (u16*)p; p += (size_t)H_ * H_ * 2;
  u16* W1T  = (u16*)p; p += (size_t)F_ * H_ * 2;
  u16* W2T  = (u16*)p; p += (size_t)H_ * F_ * 2;
  u16* WgxT = (u16*)p; p += (size_t)(4 * H_) * (2 * H_) * 2;
  u16* WhT  = (u16*)p; p += (size_t)(4 * H_) * H_ * 2;
  u16* qb   = (u16*)p; p += (size_t)TB_ * H_ * 2;
  u16* kb   = (u16*)p; p += (size_t)SB_ * H_ * 2;
  u16* vb   = (u16*)p; p += (size_t)SB_ * H_ * 2;
  u16* ctxb = (u16*)p; p += (size_t)TB_ * H_ * 2;
  u16* xs   = (u16*)p; p += (size_t)TB_ * (2 * H_) * 2;
  u16* h1   = (u16*)p; p += (size_t)TB_ * F_ * 2;    // FFN hidden; reused as g_x
  u16* hb16 = (u16*)p; p += (size_t)2 * 32768 * 2;   // raw bf16 h, double-buffered
  u32* sent = (u32*)p; p += (size_t)2 * 256 * 4;     // per-producer-wave sentinels
  u32* gxs  = (u32*)p; p += (size_t)512 * 4;         // gate-tile ready sentinels
  u16* gx   = h1;

  // ---- launch 1: fused prep (sentinel/gxs zero + casts + transposes) ----
  prep_all<<<dim3(NB_PREP), dim3(256), 0, stream>>>(
      x, mem, Wq, Wk, Wv, Wo, W1, W2, Wg,
      xb, memb, WqT, WkT, WvT, WoT, W1T, W2T, WgxT, WhT, sent, gxs);

  // ---- launch 2: batched GEMMs {q, k, v, ffn1} ----
  GBatch gb1 = {};
  gb1.j[0] = { xb,   WqT, qb, bq,  H_, H_, 0, H_ / 256, (TB_ / 256) * (H_ / 256), 0.125f };
  gb1.j[1] = { memb, WkT, kb, bk,  H_, H_, 0, H_ / 256, (SB_ / 256) * (H_ / 256), 1.0f   };
  gb1.j[2] = { memb, WvT, vb, bv,  H_, H_, 0, H_ / 256, (SB_ / 256) * (H_ / 256), 1.0f   };
  gb1.j[3] = { xb,   W1T, h1, b1f, H_, F_, 1, F_ / 256, (TB_ / 256) * (F_ / 256), 1.0f   };
  gb1.starts[0] = 0;
  gb1.starts[1] = gb1.j[0].nblk;
  gb1.starts[2] = gb1.starts[1] + gb1.j[1].nblk;
  gb1.starts[3] = gb1.starts[2] + gb1.j[2].nblk;
  gb1.njobs = 4;
  const int nb1 = gb1.starts[3] + gb1.j[3].nblk;   // 768
  gemm256<<<dim3(nb1), dim3(512), 0, stream>>>(gb1);

  // ---- launch 3: attention ----
  attn_kernel<<<dim3(B_ * NH_), dim3(256), 0, stream>>>(qb, kb, vb, src_bias, ctxb);

  // ---- launch 4: batched GEMMs {o-proj, ffn2} (o-proj hides in ffn2's shadow)
  GBatch gb2 = {};
  gb2.j[0] = { ctxb, WoT, xs + H_, bo,   H_, 2 * H_, 0, H_ / 256, (TB_ / 256) * (H_ / 256), 1.0f };
  gb2.j[1] = { h1,   W2T, xs,      b2f_, F_, 2 * H_, 0, H_ / 256, (TB_ / 256) * (H_ / 256), 1.0f };
  gb2.starts[0] = 0;
  gb2.starts[1] = gb2.j[0].nblk;
  gb2.njobs = 2;
  const int nb2 = gb2.starts[1] + gb2.j[1].nblk;   // 256
  gemm256<<<dim3(nb2), dim3(512), 0, stream>>>(gb2);

  // ---- launch 5: fused gate GEMM + persistent LSTM (overlapped) ----
  GBatch gb3 = {};
  gb3.j[0] = { xs, WgxT, gx, bg, 2 * H_, 4 * H_, 0, 16, 512, 1.0f };
  gb3.starts[0] = 0;
  gb3.njobs = 1;
  gate_lstm<<<dim3(64 + 512), dim3(512), 0, stream>>>(
      gb3, gx, WhT, hb16, sent, gxs, out);
}

// Round 13
// 1522.841 us; speedup vs baseline: 1.1259x; 1.1259x over previous
//
#include <hip/hip_runtime.h>
#include <cstdint>
#include <cstddef>

// Problem constants
#define T_  256
#define S_  128
#define B_  32
#define H_  1024
#define NH_ 16
#define D_  64
#define F_  4096
#define TB_ (T_*B_)   // 8192
#define SB_ (S_*B_)   // 4096

typedef unsigned short u16;
typedef unsigned int   u32;
typedef unsigned long long u64;
typedef __attribute__((ext_vector_type(8))) short s16x8;   // 8 bf16 (4 VGPRs)
typedef __attribute__((ext_vector_type(4))) float f32x4;
typedef __attribute__((ext_vector_type(4))) u32  u32x4;

static __device__ __forceinline__ float b2f(u16 u) {
  union { u32 i; float f; } cv; cv.i = ((u32)u) << 16; return cv.f;
}
static __device__ __forceinline__ u16 f2b(float f) {
  union { float f; u32 i; } cv; cv.f = f;
  u32 u = cv.i;
  u32 r = (u + 0x7fffu + ((u >> 16) & 1u)) >> 16;   // RNE
  return (u16)r;
}
static __device__ __forceinline__ float sigm(float x) {
  return 1.0f / (1.0f + __expf(-x));
}
static __device__ __forceinline__ float tanh_fast(float x) {
  float e2 = __expf(2.0f * x);
  return 1.0f - 2.0f / (e2 + 1.0f);
}

// async global->LDS DMA, 16B per lane
typedef const __attribute__((address_space(1))) void* gvoidp;
typedef __attribute__((address_space(3))) void* lvoidp;
static __device__ __forceinline__ void gl_lds16(const void* g, void* l) {
  __builtin_amdgcn_global_load_lds((gvoidp)g, (lvoidp)l, 16, 0, 0);
}

// ================= fused preprocessing =================
static __device__ __forceinline__ void cast_task(const float* __restrict__ in,
                                                 u16* __restrict__ out, int lb, int tid) {
  int i = lb * 256 + tid;
  float4 v = reinterpret_cast<const float4*>(in)[i];
  ushort4 o;
  o.x = f2b(v.x); o.y = f2b(v.y); o.z = f2b(v.z); o.w = f2b(v.w);
  reinterpret_cast<ushort4*>(out)[i] = o;
}

static __device__ __forceinline__ void tr32(const float* __restrict__ in,
                                            u16* __restrict__ out,
                                            int R, int C, int lin, int tid,
                                            float tile[32][33]) {
  const int gx = C >> 5;
  const int bx = lin % gx, by = lin / gx;
  const int c0 = bx << 5, r0 = by << 5;
  const int tx = tid & 31, ty = tid >> 5;   // ty 0..7
  #pragma unroll
  for (int k = 0; k < 32; k += 8)
    tile[ty + k][tx] = in[(size_t)(r0 + ty + k) * C + c0 + tx];
  __syncthreads();
  #pragma unroll
  for (int k = 0; k < 32; k += 8)
    out[(size_t)(c0 + ty + k) * R + r0 + tx] = f2b(tile[tx][ty + k]);
}

// block ranges (compile-time)
#define NB_SENT 1
#define NB_CX   8192
#define NB_CM   4096
#define NB_TSQ  1024
#define NB_TW1  4096
#define NB_TW2  4096
#define NB_TGX  8192
#define NB_TWH  4096
#define NB_PREP (NB_SENT + NB_CX + NB_CM + 4*NB_TSQ + NB_TW1 + NB_TW2 + NB_TGX + NB_TWH)

__global__ __launch_bounds__(256) void prep_all(
    const float* __restrict__ x, const float* __restrict__ mem,
    const float* __restrict__ Wq, const float* __restrict__ Wk,
    const float* __restrict__ Wv, const float* __restrict__ Wo,
    const float* __restrict__ W1, const float* __restrict__ W2,
    const float* __restrict__ Wg,
    u16* __restrict__ xb, u16* __restrict__ memb,
    u16* __restrict__ WqT, u16* __restrict__ WkT, u16* __restrict__ WvT,
    u16* __restrict__ WoT, u16* __restrict__ W1T, u16* __restrict__ W2T,
    u16* __restrict__ WgxT, u16* __restrict__ WhT, u32* __restrict__ sent)
{
  __shared__ float tile[32][33];
  int b = blockIdx.x;
  const int tid = threadIdx.x;
  if (b < NB_SENT) { sent[tid] = 0; sent[tid + 256] = 0; return; }
  b -= NB_SENT;
  if (b < NB_CX) { cast_task(x, xb, b, tid); return; }      b -= NB_CX;
  if (b < NB_CM) { cast_task(mem, memb, b, tid); return; }  b -= NB_CM;
  if (b < NB_TSQ) { tr32(Wq, WqT, H_, H_, b, tid, tile); return; }  b -= NB_TSQ;
  if (b < NB_TSQ) { tr32(Wk, WkT, H_, H_, b, tid, tile); return; }  b -= NB_TSQ;
  if (b < NB_TSQ) { tr32(Wv, WvT, H_, H_, b, tid, tile); return; }  b -= NB_TSQ;
  if (b < NB_TSQ) { tr32(Wo, WoT, H_, H_, b, tid, tile); return; }  b -= NB_TSQ;
  if (b < NB_TW1) { tr32(W1, W1T, H_, F_, b, tid, tile); return; }  b -= NB_TW1;
  if (b < NB_TW2) { tr32(W2, W2T, F_, H_, b, tid, tile); return; }  b -= NB_TW2;
  if (b < NB_TGX) { tr32(Wg, WgxT, 2 * H_, 4 * H_, b, tid, tile); return; } b -= NB_TGX;
  tr32(Wg + (size_t)(2 * H_) * (4 * H_), WhT, H_, 4 * H_, b, tid, tile);
}

// ================= GEMM 256x256 / BK=64, 4-phase counted-vmcnt schedule =====
#define SBAR      asm volatile("s_barrier" ::: "memory")
#define VMCNT4    asm volatile("s_waitcnt vmcnt(4)" ::: "memory")
#define VMCNT0    asm volatile("s_waitcnt vmcnt(0)" ::: "memory")

struct GJob {
  const u16* A; const u16* Bt; u16* Out; const float* bias;
  int Kdim; int ostride; int relu; int gridx; int nblk; float scale;
};
struct GBatch { GJob j[4]; int starts[4]; int njobs; };

// stage one [256][32] region (rows row0.., k = kt*64+kh*32..) into lds_region
static __device__ __forceinline__ void stage_region(
    const u16* __restrict__ src, int Kdim, int row0,
    int kt, int kh, char* lds_region, int tid) {
  const int w  = tid >> 6;
  const int r  = tid >> 2;                  // 0..127
  const int cs = (tid & 3) ^ ((tid >> 3) & 3);   // pre-swizzled source chunk
  const int kbase = kt * 64 + kh * 32 + cs * 8;
  gl_lds16(src + (size_t)(row0 + r) * Kdim + kbase,        lds_region + w * 1024);
  gl_lds16(src + (size_t)(row0 + 128 + r) * Kdim + kbase,  lds_region + 8192 + w * 1024);
}

static __device__ __forceinline__ s16x8 ldsf(const char* sm, int base, int row, int quad) {
  return *(const s16x8*)(sm + base + row * 64 + ((quad ^ ((row >> 1) & 3)) << 4));
}

__global__ __launch_bounds__(512, 2) void gemm256(GBatch gb)
{
  __shared__ __align__(16) u16 smem[65536];   // 128 KB
  char* sm = (char*)smem;
  const int bid = blockIdx.x;
  int ji = 0;
  #pragma unroll
  for (int t = 1; t < 4; t++)
    if (t < gb.njobs && bid >= gb.starts[t]) ji = t;
  const GJob J = gb.j[ji];
  const int lin = bid - gb.starts[ji];
  // bijective XCD swizzle (nblk % 8 == 0 for all jobs; starts % 8 == 0)
  const int wg = (lin & 7) * (J.nblk >> 3) + (lin >> 3);
  const int bx = wg % J.gridx, by = wg / J.gridx;
  const int bm = by << 8, bn = bx << 8;

  const int tid = threadIdx.x;
  const int wavei = tid >> 6, lane = tid & 63;
  const int quad = lane >> 4, l16 = lane & 15;
  const int wm = wavei >> 2, wn = wavei & 3;
  const int NT = J.Kdim >> 6;
  const int arow = wm * 128;
  const int brow = wn * 64;

  f32x4 acc[8][4] = {};

  // prologue: stage tile 0 (order matters for vmcnt: k0 regions first)
  stage_region(J.A,  J.Kdim, bm, 0, 0, sm + 0,     tid);
  stage_region(J.Bt, J.Kdim, bn, 0, 0, sm + 32768, tid);
  stage_region(J.A,  J.Kdim, bm, 0, 1, sm + 16384, tid);
  stage_region(J.Bt, J.Kdim, bn, 0, 1, sm + 49152, tid);
  VMCNT4;          // A-k0, B-k0 of tile 0 landed; k1 regions still in flight
  SBAR;

  for (int kt = 0; kt < NT; kt++) {
    const int p = (kt & 1) << 16;          // current buffer
    const int q = p ^ 65536;               // staging buffer
    const int Ab = p, Bb = p + 32768;
    const bool st = (kt + 1 < NT);
    s16x8 af[8], b0, b1;

    // ---- P1: read A[all mi][k0] + B[n0,n1][k0]; stage A-k0(kt+1) ----
    #pragma unroll
    for (int mi = 0; mi < 8; mi++)
      af[mi] = ldsf(sm, Ab, arow + mi * 16 + l16, quad);
    b0 = ldsf(sm, Bb, brow + l16, quad);
    b1 = ldsf(sm, Bb, brow + 16 + l16, quad);
    if (st) stage_region(J.A, J.Kdim, bm, kt + 1, 0, sm + q, tid);
    SBAR;
    __builtin_amdgcn_s_setprio(1);
    #pragma unroll
    for (int mi = 0; mi < 8; mi++) {
      acc[mi][0] = __builtin_amdgcn_mfma_f32_16x16x32_bf16(af[mi], b0, acc[mi][0], 0, 0, 0);
      acc[mi][1] = __builtin_amdgcn_mfma_f32_16x16x32_bf16(af[mi], b1, acc[mi][1], 0, 0, 0);
    }
    __builtin_amdgcn_s_setprio(0);
    SBAR;

    // ---- P2: read B[n2,n3][k0]; stage B-k0(kt+1); wait k1 of THIS tile ----
    b0 = ldsf(sm, Bb, brow + 32 + l16, quad);
    b1 = ldsf(sm, Bb, brow + 48 + l16, quad);
    if (st) stage_region(J.Bt, J.Kdim, bn, kt + 1, 0, sm + q + 32768, tid);
    SBAR;
    __builtin_amdgcn_s_setprio(1);
    #pragma unroll
    for (int mi = 0; mi < 8; mi++) {
      acc[mi][2] = __builtin_amdgcn_mfma_f32_16x16x32_bf16(af[mi], b0, acc[mi][2], 0, 0, 0);
      acc[mi][3] = __builtin_amdgcn_mfma_f32_16x16x32_bf16(af[mi], b1, acc[mi][3], 0, 0, 0);
    }
    __builtin_amdgcn_s_setprio(0);
    if (st) { VMCNT4; } else { VMCNT0; }   // A-k1,B-k1 of tile kt landed
    SBAR;

    // ---- P3: read A[all mi][k1] + B[n0,n1][k1]; stage A-k1(kt+1) ----
    const int Ab1 = Ab + 16384, Bb1 = Bb + 16384;
    #pragma unroll
    for (int mi = 0; mi < 8; mi++)
      af[mi] = ldsf(sm, Ab1, arow + mi * 16 + l16, quad);
    b0 = ldsf(sm, Bb1, brow + l16, quad);
    b1 = ldsf(sm, Bb1, brow + 16 + l16, quad);
    if (st) stage_region(J.A, J.Kdim, bm, kt + 1, 1, sm + q + 16384, tid);
    SBAR;
    __builtin_amdgcn_s_setprio(1);
    #pragma unroll
    for (int mi = 0; mi < 8; mi++) {
      acc[mi][0] = __builtin_amdgcn_mfma_f32_16x16x32_bf16(af[mi], b0, acc[mi][0], 0, 0, 0);
      acc[mi][1] = __builtin_amdgcn_mfma_f32_16x16x32_bf16(af[mi], b1, acc[mi][1], 0, 0, 0);
    }
    __builtin_amdgcn_s_setprio(0);
    SBAR;

    // ---- P4: read B[n2,n3][k1]; stage B-k1(kt+1); wait k0 of NEXT tile ----
    b0 = ldsf(sm, Bb1, brow + 32 + l16, quad);
    b1 = ldsf(sm, Bb1, brow + 48 + l16, quad);
    if (st) stage_region(J.Bt, J.Kdim, bn, kt + 1, 1, sm + q + 49152, tid);
    SBAR;
    __builtin_amdgcn_s_setprio(1);
    #pragma unroll
    for (int mi = 0; mi < 8; mi++) {
      acc[mi][2] = __builtin_amdgcn_mfma_f32_16x16x32_bf16(af[mi], b0, acc[mi][2], 0, 0, 0);
      acc[mi][3] = __builtin_amdgcn_mfma_f32_16x16x32_bf16(af[mi], b1, acc[mi][3], 0, 0, 0);
    }
    __builtin_amdgcn_s_setprio(0);
    if (st) { VMCNT4; }                    // A-k0,B-k0 of kt+1 landed
    SBAR;
  }

  // epilogue: bias + scale + relu
  #pragma unroll
  for (int mi = 0; mi < 8; mi++) {
    #pragma unroll
    for (int nj = 0; nj < 4; nj++) {
      const int colo = bn + wn * 64 + nj * 16 + l16;
      const float bv = J.bias[colo];
      #pragma unroll
      for (int r = 0; r < 4; r++) {
        const int rowo = bm + wm * 128 + mi * 16 + quad * 4 + r;
        float vv = (acc[mi][nj][r] + bv) * J.scale;
        if (J.relu) vv = fmaxf(vv, 0.0f);
        J.Out[(size_t)rowo * J.ostride + colo] = f2b(vv);
      }
    }
  }
}

// ---------------- attention: single-pass online softmax + defer-rescale -----
// v17: was 2 full QK^T passes (dot recomputed in pass 2). Now one pass with
// running (m,l,of) and T13 defer-rescale: rescale of[] only when dot exceeds
// m+8 (weights bounded by e^8; fp32 accumulators have ample headroom; result
// mathematically identical to exact softmax). Cuts ~8k of ~24k VALU ops and
// half the exps per thread.
__global__ __launch_bounds__(256) void attn_kernel(
    const u16* __restrict__ q, const u16* __restrict__ k, const u16* __restrict__ v,
    const float* __restrict__ src_bias, u16* __restrict__ ctx)
{
  __shared__ u16 ks[S_ * D_];
  __shared__ u16 vs[S_ * D_];
  const int b  = blockIdx.x >> 4;
  const int nh = blockIdx.x & 15;
  const int tid = threadIdx.x;

  for (int i = tid; i < (S_ * D_) / 8; i += 256) {
    int s = i >> 3, c = (i & 7) * 8;
    *(uint4*)&ks[s * D_ + c] = *(const uint4*)&k[((size_t)(s * B_ + b)) * H_ + nh * D_ + c];
    *(uint4*)&vs[s * D_ + c] = *(const uint4*)&v[((size_t)(s * B_ + b)) * H_ + nh * D_ + c];
  }
  __syncthreads();

  const int t = tid;
  float qf[D_];
  const u16* qp = &q[((size_t)(t * B_ + b)) * H_ + nh * D_];
  #pragma unroll
  for (int c8 = 0; c8 < D_; c8 += 8) {
    uint4 qv = *(const uint4*)&qp[c8];
    const u16* pu = (const u16*)&qv;
    #pragma unroll
    for (int j = 0; j < 8; j++) qf[c8 + j] = b2f(pu[j]);
  }
  const float* bias = src_bias + b * S_;

  float m = -1e30f, l = 0.0f;
  float of[D_] = {};
  for (int s = 0; s < S_; s++) {
    float dot = 0.0f;
    #pragma unroll
    for (int d = 0; d < D_; d++) dot += qf[d] * b2f(ks[s * D_ + d]);
    dot += bias[s];
    if (dot > m + 8.0f) {                 // defer-rescale (rare)
      const float sc = __expf(m - dot);   // first iter: exp(-inf)=0 zeroes l,of
      l *= sc;
      #pragma unroll
      for (int d = 0; d < D_; d++) of[d] *= sc;
      m = dot;
    }
    const float w = __expf(dot - m);      // bounded by e^8
    l += w;
    #pragma unroll
    for (int d = 0; d < D_; d++) of[d] += w * b2f(vs[s * D_ + d]);
  }
  const float inv = 1.0f / l;
  u16* op = &ctx[((size_t)(t * B_ + b)) * H_ + nh * D_];
  #pragma unroll
  for (int c8 = 0; c8 < D_; c8 += 8) {
    u16 tmp[8];
    #pragma unroll
    for (int j = 0; j < 8; j++) tmp[j] = f2b(of[c8 + j] * inv);
    *(uint4*)&op[c8] = *(const uint4*)tmp;
  }
}

// ---------------- persistent LSTM v9 (best: 8.2k cy/step; ladder closed) ----
// Producer: bf16 data stores (agent) -> own-wave vmcnt(0) ack -> per-wave
// sentinel. Consumer: sentinel spin (1KB set) -> payload read EXACTLY once
// with counted vmcnt ladder. Drain-free stamped variants regressed 1.5-2.3x
// (cross-XCD visibility ~3k cy; retries re-read the full wire). v16's fused
// gate-GEMM overlap also regressed (+62us on the LSTM path from coherent g_x
// loads + L2 interference). Keep as-is.
#define ISSUE2(K) { \
  const u16* b0_ = hb + ((size_t)(wave * 16 + (K) * 2 + (quad >> 1))) * 512 + \
                   (quad & 1) * 8 + l16 * 16; \
  asm volatile("global_load_dwordx4 %0, %1, off sc0 sc1" : "=v"(ba[K][0]) : "v"(b0_) : "memory"); \
  asm volatile("global_load_dwordx4 %0, %1, off sc0 sc1" : "=v"(ba[K][1]) : "v"(b0_ + 256) : "memory"); }

#define DO_MFMA(A0,A1,KC)                                                           \
  { _Pragma("unroll") for (int g_ = 0; g_ < 3; g_++) {                              \
      s16x8 wf_ = *(const s16x8*)&Wl[wave][((g_ * 8 + (KC)) * 64 + lane) * 8];      \
      acc[g_][0] = __builtin_amdgcn_mfma_f32_16x16x32_bf16(A0, wf_, acc[g_][0], 0, 0, 0); \
      acc[g_][1] = __builtin_amdgcn_mfma_f32_16x16x32_bf16(A1, wf_, acc[g_][1], 0, 0, 0); } \
    acc[3][0] = __builtin_amdgcn_mfma_f32_16x16x32_bf16(A0, wo[KC], acc[3][0], 0, 0, 0);  \
    acc[3][1] = __builtin_amdgcn_mfma_f32_16x16x32_bf16(A1, wo[KC], acc[3][1], 0, 0, 0); }

#define CONSUME(K, NSTR) { \
  asm volatile("s_waitcnt vmcnt(" NSTR ")" ::: "memory"); \
  __builtin_amdgcn_sched_barrier(0); \
  DO_MFMA(ba[K][0], ba[K][1], K); }

__global__ __launch_bounds__(256, 1) void lstm_persistent(
    const u16* __restrict__ g_x, const u16* __restrict__ WhT,
    u16* __restrict__ hb16, u32* __restrict__ sent, float* __restrict__ out)
{
  __shared__ __align__(16) u16 Wl[4][3 * 8 * 64 * 8];  // gates 0-2: 96 KB
  __shared__ float P[4][4][32][17];                     // partials: 34.8 KB
  const int bk = blockIdx.x, tid = threadIdx.x;
  const int wave = tid >> 6, lane = tid & 63;
  const int quad = lane >> 4, l16 = lane & 15;

  // one-time weight staging, directly from WhT (rearranged addressing)
  for (int i = lane; i < 3 * 8 * 64; i += 64) {
    const int g  = (i >> 9) & 3;
    const int kc = (i >> 6) & 7;
    const int row = g * H_ + bk * 16 + (lane & 15);
    const int col = wave * 256 + kc * 32 + (lane >> 4) * 8;
    *(uint4*)&Wl[wave][i * 8] = *(const uint4*)&WhT[(size_t)row * H_ + col];
  }
  s16x8 wo[8];                       // gate-3 weights in registers
  {
    const int row = 3 * H_ + bk * 16 + (lane & 15);
    const int colb = wave * 256 + (lane >> 4) * 8;
    #pragma unroll
    for (int kc = 0; kc < 8; kc++)
      wo[kc] = *(const s16x8*)&WhT[(size_t)row * H_ + colb + kc * 32];
  }
  __syncthreads();

  const int pb = tid >> 4, pc = tid & 15;
  const int col = bk * 16 + pc;
  float creg[2] = {0.0f, 0.0f};

  float gxp[2][4];
  #pragma unroll
  for (int ii = 0; ii < 2; ii++)
    #pragma unroll
    for (int g = 0; g < 4; g++)
      gxp[ii][g] = b2f(g_x[((size_t)(pb + ii * 16)) * (4 * H_) + g * H_ + col]);

  s16x8 ba[8][2];   // all 8 k-banks in flight (64 VGPRs), static indexing

  for (int t = 0; t < T_; t++) {
    if (t > 0) {
      const u32 st = (u32)t;                       // h(t-1) published with value t
      const u16* hb = hb16 + ((t & 1) ^ 1) * 32768;

      // ---- acquire: wait for the 64 producer-wave sentinels this wave needs
      { const u32* sp = sent + ((size_t)(((t & 1) ^ 1) * 256 + wave * 64 + lane));
        u32 sv;
        do {
          asm volatile("global_load_dword %0, %1, off sc0 sc1\n\ts_waitcnt vmcnt(0)"
                       : "=v"(sv) : "v"(sp) : "memory");
        } while (!__all(sv == st)); }

      f32x4 acc[4][2] = {};
      // issue all 16 data loads (read-once), then counted-vmcnt drain + MFMA
      ISSUE2(0) ISSUE2(1) ISSUE2(2) ISSUE2(3)
      ISSUE2(4) ISSUE2(5) ISSUE2(6) ISSUE2(7)
      CONSUME(0, "14") CONSUME(1, "12") CONSUME(2, "10") CONSUME(3, "8")
      CONSUME(4, "6")  CONSUME(5, "4")  CONSUME(6, "2")  CONSUME(7, "0")

      #pragma unroll
      for (int g = 0; g < 4; g++)
        #pragma unroll
        for (int mt = 0; mt < 2; mt++)
          #pragma unroll
          for (int r = 0; r < 4; r++)
            P[wave][g][mt * 16 + quad * 4 + r][l16] = acc[g][mt][r];
    }
    __syncthreads();

    // reduce partials into gate sums (register-only after this)
    float gs[2][4];
    #pragma unroll
    for (int ii = 0; ii < 2; ii++) {
      const int b_ = pb + ii * 16;
      #pragma unroll
      for (int g = 0; g < 4; g++) {
        float s = gxp[ii][g];
        if (t > 0) s += P[0][g][b_][pc] + P[1][g][b_][pc] + P[2][g][b_][pc] + P[3][g][b_][pc];
        gs[ii][g] = s;
      }
    }
    __syncthreads();   // P consumed; next step may overwrite

    // pointwise
    float hn[2], cn[2];
    #pragma unroll
    for (int ii = 0; ii < 2; ii++) {
      const float iv = sigm(gs[ii][0]);
      const float jv = tanh_fast(gs[ii][1]);
      const float fv = sigm(gs[ii][2]);
      const float ov = sigm(gs[ii][3]);
      cn[ii] = fv * creg[ii] + iv * jv;
      hn[ii] = ov * cn[ii];
      creg[ii] = cn[ii];
    }

    // ---- release: bf16 data stores (agent) -> own-wave drain -> sentinel ----
    {
      u32 lo0 = f2b(hn[0]), lo1 = f2b(hn[1]);
      u32 hi0 = __shfl_down(lo0, 1), hi1 = __shfl_down(lo1, 1);
      if ((pc & 1) == 0) {
        u32* hw32 = (u32*)(hb16 + (t & 1) * 32768);
        u32 dw0 = lo0 | (hi0 << 16);
        u32 dw1 = lo1 | (hi1 << 16);
        __hip_atomic_store(&hw32[(size_t)bk * 256 + pb * 8 + (pc >> 1)], dw0,
                           __ATOMIC_RELAXED, __HIP_MEMORY_SCOPE_AGENT);
        __hip_atomic_store(&hw32[(size_t)bk * 256 + (pb + 16) * 8 + (pc >> 1)], dw1,
                           __ATOMIC_RELAXED, __HIP_MEMORY_SCOPE_AGENT);
      }
      asm volatile("s_waitcnt vmcnt(0)" ::: "memory");
      if (lane == 0)
        __hip_atomic_store(&sent[(size_t)(t & 1) * 256 + bk * 4 + wave], (u32)(t + 1),
                           __ATOMIC_RELAXED, __HIP_MEMORY_SCOPE_AGENT);
    }

    // deferred: fp32 outputs + next g_x prefetch (off critical path)
    #pragma unroll
    for (int ii = 0; ii < 2; ii++) {
      const int b_ = pb + ii * 16;
      out[(size_t)t * (B_ * H_) + b_ * H_ + col] = hn[ii];
      if (t == T_ - 1) {
        out[(size_t)T_ * B_ * H_ + b_ * H_ + col] = cn[ii];              // c_f
        out[(size_t)T_ * B_ * H_ + B_ * H_ + b_ * H_ + col] = hn[ii];    // h_f
      }
    }
    if (t < T_ - 1) {
      #pragma unroll
      for (int ii = 0; ii < 2; ii++)
        #pragma unroll
        for (int g = 0; g < 4; g++)
          gxp[ii][g] = b2f(g_x[((size_t)(t + 1) * B_ + pb + ii * 16) * (4 * H_) + g * H_ + col]);
    }
  }
}

extern "C" void kernel_launch(void* const* d_in, const int* in_sizes, int n_in,
                              void* d_out, int out_size, void* d_ws, size_t ws_size,
                              hipStream_t stream)
{
  const float* x        = (const float*)d_in[0];
  const float* src_bias = (const float*)d_in[1];
  const float* mem      = (const float*)d_in[3];
  const float* Wq = (const float*)d_in[4];  const float* bq = (const float*)d_in[5];
  const float* Wk = (const float*)d_in[6];  const float* bk = (const float*)d_in[7];
  const float* Wv = (const float*)d_in[8];  const float* bv = (const float*)d_in[9];
  const float* Wo = (const float*)d_in[10]; const float* bo = (const float*)d_in[11];
  const float* W1 = (const float*)d_in[12]; const float* b1f = (const float*)d_in[13];
  const float* W2 = (const float*)d_in[14]; const float* b2f_ = (const float*)d_in[15];
  const float* Wg = (const float*)d_in[16]; const float* bg = (const float*)d_in[17];
  float* out = (float*)d_out;

  char* p = (char*)d_ws;
  u16* xb   = (u16*)p; p += (size_t)TB_ * H_ * 2;
  u16* memb = (u16*)p; p += (size_t)SB_ * H_ * 2;
  u16* WqT  = (u16*)p; p += (size_t)H_ * H_ * 2;
  u16* WkT  = (u16*)p; p += (size_t)H_ * H_ * 2;
  u16* WvT  = (u16*)p; p += (size_t)H_ * H_ * 2;
  u16* WoT  = (u16*)p; p += (size_t)H_ * H_ * 2;
  u16* W1T  = (u16*)p; p += (size_t)F_ * H_ * 2;
  u16* W2T  = (u16*)p; p += (size_t)H_ * F_ * 2;
  u16* WgxT = (u16*)p; p += (size_t)(4 * H_) * (2 * H_) * 2;
  u16* WhT  = (u16*)p; p += (size_t)(4 * H_) * H_ * 2;
  u16* qb   = (u16*)p; p += (size_t)TB_ * H_ * 2;
  u16* kb   = (u16*)p; p += (size_t)SB_ * H_ * 2;
  u16* vb   = (u16*)p; p += (size_t)SB_ * H_ * 2;
  u16* ctxb = (u16*)p; p += (size_t)TB_ * H_ * 2;
  u16* xs   = (u16*)p; p += (size_t)TB_ * (2 * H_) * 2;
  u16* h1   = (u16*)p; p += (size_t)TB_ * F_ * 2;    // FFN hidden; reused as g_x
  u16* hb16 = (u16*)p; p += (size_t)2 * 32768 * 2;   // raw bf16 h, double-buffered
  u32* sent = (u32*)p; p += (size_t)2 * 256 * 4;     // per-producer-wave sentinels
  u16* gx   = h1;

  // ---- launch 1: fused prep (sentinel zero + casts + weight transposes) ----
  prep_all<<<dim3(NB_PREP), dim3(256), 0, stream>>>(
      x, mem, Wq, Wk, Wv, Wo, W1, W2, Wg,
      xb, memb, WqT, WkT, WvT, WoT, W1T, W2T, WgxT, WhT, sent);

  // ---- launch 2: batched GEMMs {q, k, v, ffn1} ----
  GBatch gb1 = {};
  gb1.j[0] = { xb,   WqT, qb, bq,  H_, H_, 0, H_ / 256, (TB_ / 256) * (H_ / 256), 0.125f };
  gb1.j[1] = { memb, WkT, kb, bk,  H_, H_, 0, H_ / 256, (SB_ / 256) * (H_ / 256), 1.0f   };
  gb1.j[2] = { memb, WvT, vb, bv,  H_, H_, 0, H_ / 256, (SB_ / 256) * (H_ / 256), 1.0f   };
  gb1.j[3] = { xb,   W1T, h1, b1f, H_, F_, 1, F_ / 256, (TB_ / 256) * (F_ / 256), 1.0f   };
  gb1.starts[0] = 0;
  gb1.starts[1] = gb1.j[0].nblk;
  gb1.starts[2] = gb1.starts[1] + gb1.j[1].nblk;
  gb1.starts[3] = gb1.starts[2] + gb1.j[2].nblk;
  gb1.njobs = 4;
  const int nb1 = gb1.starts[3] + gb1.j[3].nblk;   // 768
  gemm256<<<dim3(nb1), dim3(512), 0, stream>>>(gb1);

  // ---- launch 3: attention ----
  attn_kernel<<<dim3(B_ * NH_), dim3(256), 0, stream>>>(qb, kb, vb, src_bias, ctxb);

  // ---- launch 4: batched GEMMs {o-proj, ffn2} ----
  GBatch gb2 = {};
  gb2.j[0] = { ctxb, WoT, xs + H_, bo,   H_, 2 * H_, 0, H_ / 256, (TB_ / 256) * (H_ / 256), 1.0f };
  gb2.j[1] = { h1,   W2T, xs,      b2f_, F_, 2 * H_, 0, H_ / 256, (TB_ / 256) * (H_ / 256), 1.0f };
  gb2.starts[0] = 0;
  gb2.starts[1] = gb2.j[0].nblk;
  gb2.njobs = 2;
  const int nb2 = gb2.starts[1] + gb2.j[1].nblk;   // 256
  gemm256<<<dim3(nb2), dim3(512), 0, stream>>>(gb2);

  // ---- launch 5: gate x-part GEMM ----
  GBatch gb3 = {};
  gb3.j[0] = { xs, WgxT, gx, bg, 2 * H_, 4 * H_, 0, 4 * H_ / 256, (TB_ / 256) * (4 * H_ / 256), 1.0f };
  gb3.starts[0] = 0;
  gb3.njobs = 1;
  gemm256<<<dim3(gb3.j[0].nblk), dim3(512), 0, stream>>>(gb3);   // 512

  // ---- launch 6: persistent LSTM (v9 sync structure) ----
  lstm_persistent<<<dim3(64), dim3(256), 0, stream>>>(gx, WhT, hb16, sent, out);
}

// Round 14
// 1492.371 us; speedup vs baseline: 1.1489x; 1.0204x over previous
//
#include <hip/hip_runtime.h>
#include <cstdint>
#include <cstddef>

// Problem constants
#define T_  256
#define S_  128
#define B_  32
#define H_  1024
#define NH_ 16
#define D_  64
#define F_  4096
#define TB_ (T_*B_)   // 8192
#define SB_ (S_*B_)   // 4096

typedef unsigned short u16;
typedef unsigned int   u32;
typedef unsigned long long u64;
typedef __attribute__((ext_vector_type(8))) short s16x8;   // 8 bf16 (4 VGPRs)
typedef __attribute__((ext_vector_type(4))) float f32x4;
typedef __attribute__((ext_vector_type(4))) u32  u32x4;

static __device__ __forceinline__ float b2f(u16 u) {
  union { u32 i; float f; } cv; cv.i = ((u32)u) << 16; return cv.f;
}
static __device__ __forceinline__ u16 f2b(float f) {
  union { float f; u32 i; } cv; cv.f = f;
  u32 u = cv.i;
  u32 r = (u + 0x7fffu + ((u >> 16) & 1u)) >> 16;   // RNE
  return (u16)r;
}
static __device__ __forceinline__ float sigm(float x) {
  return 1.0f / (1.0f + __expf(-x));
}
static __device__ __forceinline__ float tanh_fast(float x) {
  float e2 = __expf(2.0f * x);
  return 1.0f - 2.0f / (e2 + 1.0f);
}

// async global->LDS DMA, 16B per lane
typedef const __attribute__((address_space(1))) void* gvoidp;
typedef __attribute__((address_space(3))) void* lvoidp;
static __device__ __forceinline__ void gl_lds16(const void* g, void* l) {
  __builtin_amdgcn_global_load_lds((gvoidp)g, (lvoidp)l, 16, 0, 0);
}

// ================= preprocessing helpers =================
static __device__ __forceinline__ void cast_task(const float* __restrict__ in,
                                                 u16* __restrict__ out, int lb, int tid) {
  int i = lb * 256 + tid;
  float4 v = reinterpret_cast<const float4*>(in)[i];
  ushort4 o;
  o.x = f2b(v.x); o.y = f2b(v.y); o.z = f2b(v.z); o.w = f2b(v.w);
  reinterpret_cast<ushort4*>(out)[i] = o;
}

static __device__ __forceinline__ void tr32(const float* __restrict__ in,
                                            u16* __restrict__ out,
                                            int R, int C, int lin, int tid,
                                            float (*tile)[33]) {
  const int gx = C >> 5;
  const int bx = lin % gx, by = lin / gx;
  const int c0 = bx << 5, r0 = by << 5;
  const int tx = tid & 31, ty = tid >> 5;   // ty 0..7
  #pragma unroll
  for (int k = 0; k < 32; k += 8)
    tile[ty + k][tx] = in[(size_t)(r0 + ty + k) * C + c0 + tx];
  __syncthreads();
  #pragma unroll
  for (int k = 0; k < 32; k += 8)
    out[(size_t)(c0 + ty + k) * R + r0 + tx] = f2b(tile[tx][ty + k]);
}

// ---- prep launch (only what gb1 needs + sentinel zero) ----
// v18: WoT/W2T/WgxT/WhT transposes (17408 tiles, ~105MB traffic) moved into
// the attention launch's shadow (attn uses 32KB LDS -> 5 blocks/CU
// co-residency; the transposes are independent of attn and consumed only by
// LATER launches -> launch-boundary coherence, no sentinels). They can't fold
// into the GEMM launch: its 128KB static LDS is allocated by EVERY block of
// the kernel, killing co-residency.
#define NB_SENT 1
#define NB_CX   8192
#define NB_CM   4096
#define NB_TSQ  1024
#define NB_TW1  4096
#define NB_PREP (NB_SENT + NB_CX + NB_CM + 3*NB_TSQ + NB_TW1)

__global__ __launch_bounds__(256) void prep_all(
    const float* __restrict__ x, const float* __restrict__ mem,
    const float* __restrict__ Wq, const float* __restrict__ Wk,
    const float* __restrict__ Wv, const float* __restrict__ W1,
    u16* __restrict__ xb, u16* __restrict__ memb,
    u16* __restrict__ WqT, u16* __restrict__ WkT, u16* __restrict__ WvT,
    u16* __restrict__ W1T, u32* __restrict__ sent)
{
  __shared__ float tile[32][33];
  int b = blockIdx.x;
  const int tid = threadIdx.x;
  if (b < NB_SENT) { sent[tid] = 0; sent[tid + 256] = 0; return; }
  b -= NB_SENT;
  if (b < NB_CX) { cast_task(x, xb, b, tid); return; }      b -= NB_CX;
  if (b < NB_CM) { cast_task(mem, memb, b, tid); return; }  b -= NB_CM;
  if (b < NB_TSQ) { tr32(Wq, WqT, H_, H_, b, tid, tile); return; }  b -= NB_TSQ;
  if (b < NB_TSQ) { tr32(Wk, WkT, H_, H_, b, tid, tile); return; }  b -= NB_TSQ;
  if (b < NB_TSQ) { tr32(Wv, WvT, H_, H_, b, tid, tile); return; }  b -= NB_TSQ;
  tr32(W1, W1T, H_, F_, b, tid, tile);
}

// ================= GEMM 256x256 / BK=64, 4-phase counted-vmcnt schedule =====
#define SBAR      asm volatile("s_barrier" ::: "memory")
#define VMCNT4    asm volatile("s_waitcnt vmcnt(4)" ::: "memory")
#define VMCNT0    asm volatile("s_waitcnt vmcnt(0)" ::: "memory")

struct GJob {
  const u16* A; const u16* Bt; u16* Out; const float* bias;
  int Kdim; int ostride; int relu; int gridx; int nblk; float scale;
};
struct GBatch { GJob j[4]; int starts[4]; int njobs; };

// stage one [256][32] region (rows row0.., k = kt*64+kh*32..) into lds_region
static __device__ __forceinline__ void stage_region(
    const u16* __restrict__ src, int Kdim, int row0,
    int kt, int kh, char* lds_region, int tid) {
  const int w  = tid >> 6;
  const int r  = tid >> 2;                  // 0..127
  const int cs = (tid & 3) ^ ((tid >> 3) & 3);   // pre-swizzled source chunk
  const int kbase = kt * 64 + kh * 32 + cs * 8;
  gl_lds16(src + (size_t)(row0 + r) * Kdim + kbase,        lds_region + w * 1024);
  gl_lds16(src + (size_t)(row0 + 128 + r) * Kdim + kbase,  lds_region + 8192 + w * 1024);
}

static __device__ __forceinline__ s16x8 ldsf(const char* sm, int base, int row, int quad) {
  return *(const s16x8*)(sm + base + row * 64 + ((quad ^ ((row >> 1) & 3)) << 4));
}

__global__ __launch_bounds__(512, 2) void gemm256(GBatch gb)
{
  __shared__ __align__(16) u16 smem[65536];   // 128 KB
  char* sm = (char*)smem;
  const int bid = blockIdx.x;
  int ji = 0;
  #pragma unroll
  for (int t = 1; t < 4; t++)
    if (t < gb.njobs && bid >= gb.starts[t]) ji = t;
  const GJob J = gb.j[ji];
  const int lin = bid - gb.starts[ji];
  // bijective XCD swizzle (nblk % 8 == 0 for all jobs; starts % 8 == 0)
  const int wg = (lin & 7) * (J.nblk >> 3) + (lin >> 3);
  const int bx = wg % J.gridx, by = wg / J.gridx;
  const int bm = by << 8, bn = bx << 8;

  const int tid = threadIdx.x;
  const int wavei = tid >> 6, lane = tid & 63;
  const int quad = lane >> 4, l16 = lane & 15;
  const int wm = wavei >> 2, wn = wavei & 3;
  const int NT = J.Kdim >> 6;
  const int arow = wm * 128;
  const int brow = wn * 64;

  f32x4 acc[8][4] = {};

  // prologue: stage tile 0 (order matters for vmcnt: k0 regions first)
  stage_region(J.A,  J.Kdim, bm, 0, 0, sm + 0,     tid);
  stage_region(J.Bt, J.Kdim, bn, 0, 0, sm + 32768, tid);
  stage_region(J.A,  J.Kdim, bm, 0, 1, sm + 16384, tid);
  stage_region(J.Bt, J.Kdim, bn, 0, 1, sm + 49152, tid);
  VMCNT4;          // A-k0, B-k0 of tile 0 landed; k1 regions still in flight
  SBAR;

  for (int kt = 0; kt < NT; kt++) {
    const int p = (kt & 1) << 16;          // current buffer
    const int q = p ^ 65536;               // staging buffer
    const int Ab = p, Bb = p + 32768;
    const bool st = (kt + 1 < NT);
    s16x8 af[8], b0, b1;

    // ---- P1: read A[all mi][k0] + B[n0,n1][k0]; stage A-k0(kt+1) ----
    #pragma unroll
    for (int mi = 0; mi < 8; mi++)
      af[mi] = ldsf(sm, Ab, arow + mi * 16 + l16, quad);
    b0 = ldsf(sm, Bb, brow + l16, quad);
    b1 = ldsf(sm, Bb, brow + 16 + l16, quad);
    if (st) stage_region(J.A, J.Kdim, bm, kt + 1, 0, sm + q, tid);
    SBAR;
    __builtin_amdgcn_s_setprio(1);
    #pragma unroll
    for (int mi = 0; mi < 8; mi++) {
      acc[mi][0] = __builtin_amdgcn_mfma_f32_16x16x32_bf16(af[mi], b0, acc[mi][0], 0, 0, 0);
      acc[mi][1] = __builtin_amdgcn_mfma_f32_16x16x32_bf16(af[mi], b1, acc[mi][1], 0, 0, 0);
    }
    __builtin_amdgcn_s_setprio(0);
    SBAR;

    // ---- P2: read B[n2,n3][k0]; stage B-k0(kt+1); wait k1 of THIS tile ----
    b0 = ldsf(sm, Bb, brow + 32 + l16, quad);
    b1 = ldsf(sm, Bb, brow + 48 + l16, quad);
    if (st) stage_region(J.Bt, J.Kdim, bn, kt + 1, 0, sm + q + 32768, tid);
    SBAR;
    __builtin_amdgcn_s_setprio(1);
    #pragma unroll
    for (int mi = 0; mi < 8; mi++) {
      acc[mi][2] = __builtin_amdgcn_mfma_f32_16x16x32_bf16(af[mi], b0, acc[mi][2], 0, 0, 0);
      acc[mi][3] = __builtin_amdgcn_mfma_f32_16x16x32_bf16(af[mi], b1, acc[mi][3], 0, 0, 0);
    }
    __builtin_amdgcn_s_setprio(0);
    if (st) { VMCNT4; } else { VMCNT0; }   // A-k1,B-k1 of tile kt landed
    SBAR;

    // ---- P3: read A[all mi][k1] + B[n0,n1][k1]; stage A-k1(kt+1) ----
    const int Ab1 = Ab + 16384, Bb1 = Bb + 16384;
    #pragma unroll
    for (int mi = 0; mi < 8; mi++)
      af[mi] = ldsf(sm, Ab1, arow + mi * 16 + l16, quad);
    b0 = ldsf(sm, Bb1, brow + l16, quad);
    b1 = ldsf(sm, Bb1, brow + 16 + l16, quad);
    if (st) stage_region(J.A, J.Kdim, bm, kt + 1, 1, sm + q + 16384, tid);
    SBAR;
    __builtin_amdgcn_s_setprio(1);
    #pragma unroll
    for (int mi = 0; mi < 8; mi++) {
      acc[mi][0] = __builtin_amdgcn_mfma_f32_16x16x32_bf16(af[mi], b0, acc[mi][0], 0, 0, 0);
      acc[mi][1] = __builtin_amdgcn_mfma_f32_16x16x32_bf16(af[mi], b1, acc[mi][1], 0, 0, 0);
    }
    __builtin_amdgcn_s_setprio(0);
    SBAR;

    // ---- P4: read B[n2,n3][k1]; stage B-k1(kt+1); wait k0 of NEXT tile ----
    b0 = ldsf(sm, Bb1, brow + 32 + l16, quad);
    b1 = ldsf(sm, Bb1, brow + 48 + l16, quad);
    if (st) stage_region(J.Bt, J.Kdim, bn, kt + 1, 1, sm + q + 49152, tid);
    SBAR;
    __builtin_amdgcn_s_setprio(1);
    #pragma unroll
    for (int mi = 0; mi < 8; mi++) {
      acc[mi][2] = __builtin_amdgcn_mfma_f32_16x16x32_bf16(af[mi], b0, acc[mi][2], 0, 0, 0);
      acc[mi][3] = __builtin_amdgcn_mfma_f32_16x16x32_bf16(af[mi], b1, acc[mi][3], 0, 0, 0);
    }
    __builtin_amdgcn_s_setprio(0);
    if (st) { VMCNT4; }                    // A-k0,B-k0 of kt+1 landed
    SBAR;
  }

  // epilogue: bias + scale + relu
  #pragma unroll
  for (int mi = 0; mi < 8; mi++) {
    #pragma unroll
    for (int nj = 0; nj < 4; nj++) {
      const int colo = bn + wn * 64 + nj * 16 + l16;
      const float bv = J.bias[colo];
      #pragma unroll
      for (int r = 0; r < 4; r++) {
        const int rowo = bm + wm * 128 + mi * 16 + quad * 4 + r;
        float vv = (acc[mi][nj][r] + bv) * J.scale;
        if (J.relu) vv = fmaxf(vv, 0.0f);
        J.Out[(size_t)rowo * J.ostride + colo] = f2b(vv);
      }
    }
  }
}

// ------- attention (single-pass online softmax) + late-weight transposes ----
// Blocks [0,512): attn. Blocks [512, 512+17408): WoT/W2T/WgxT/WhT transpose
// tiles riding in attn's shadow (32KB LDS union -> 5 blocks/CU). Consumers of
// the transposed weights are all LATER launches (gb2/gb3/lstm).
#define NB_ATTN  512
#define NB_TWO2  1024    // WoT
#define NB_TW22  4096    // W2T
#define NB_TGX2  8192    // WgxT
#define NB_TWH2  4096    // WhT
#define NB_ATTNL (NB_ATTN + NB_TWO2 + NB_TW22 + NB_TGX2 + NB_TWH2)   // 17920

__global__ __launch_bounds__(256) void attn_prep(
    const u16* __restrict__ q, const u16* __restrict__ k, const u16* __restrict__ v,
    const float* __restrict__ src_bias, u16* __restrict__ ctx,
    const float* __restrict__ Wo, const float* __restrict__ W2,
    const float* __restrict__ Wg,
    u16* __restrict__ WoT, u16* __restrict__ W2T,
    u16* __restrict__ WgxT, u16* __restrict__ WhT)
{
  __shared__ __align__(16) char shraw[32768];   // attn: ks16K+vs16K | tr: 4.2K
  const int tid = threadIdx.x;

  if (blockIdx.x >= NB_ATTN) {
    float (*tile)[33] = (float(*)[33])shraw;
    int tix = blockIdx.x - NB_ATTN;
    if (tix < NB_TWO2) { tr32(Wo, WoT, H_, H_, tix, tid, tile); return; }
    tix -= NB_TWO2;
    if (tix < NB_TW22) { tr32(W2, W2T, F_, H_, tix, tid, tile); return; }
    tix -= NB_TW22;
    if (tix < NB_TGX2) { tr32(Wg, WgxT, 2 * H_, 4 * H_, tix, tid, tile); return; }
    tix -= NB_TGX2;
    tr32(Wg + (size_t)(2 * H_) * (4 * H_), WhT, H_, 4 * H_, tix, tid, tile);
    return;
  }

  u16* ks = (u16*)shraw;
  u16* vs = ks + S_ * D_;
  const int b  = blockIdx.x >> 4;
  const int nh = blockIdx.x & 15;

  for (int i = tid; i < (S_ * D_) / 8; i += 256) {
    int s = i >> 3, c = (i & 7) * 8;
    *(uint4*)&ks[s * D_ + c] = *(const uint4*)&k[((size_t)(s * B_ + b)) * H_ + nh * D_ + c];
    *(uint4*)&vs[s * D_ + c] = *(const uint4*)&v[((size_t)(s * B_ + b)) * H_ + nh * D_ + c];
  }
  __syncthreads();

  const int t = tid;
  float qf[D_];
  const u16* qp = &q[((size_t)(t * B_ + b)) * H_ + nh * D_];
  #pragma unroll
  for (int c8 = 0; c8 < D_; c8 += 8) {
    uint4 qv = *(const uint4*)&qp[c8];
    const u16* pu = (const u16*)&qv;
    #pragma unroll
    for (int j = 0; j < 8; j++) qf[c8 + j] = b2f(pu[j]);
  }
  const float* bias = src_bias + b * S_;

  float m = -1e30f, l = 0.0f;
  float of[D_] = {};
  for (int s = 0; s < S_; s++) {
    float dot = 0.0f;
    #pragma unroll
    for (int d = 0; d < D_; d++) dot += qf[d] * b2f(ks[s * D_ + d]);
    dot += bias[s];
    if (dot > m + 8.0f) {                 // defer-rescale (rare)
      const float sc = __expf(m - dot);   // first iter: exp(-inf)=0 zeroes l,of
      l *= sc;
      #pragma unroll
      for (int d = 0; d < D_; d++) of[d] *= sc;
      m = dot;
    }
    const float w = __expf(dot - m);      // bounded by e^8
    l += w;
    #pragma unroll
    for (int d = 0; d < D_; d++) of[d] += w * b2f(vs[s * D_ + d]);
  }
  const float inv = 1.0f / l;
  u16* op = &ctx[((size_t)(t * B_ + b)) * H_ + nh * D_];
  #pragma unroll
  for (int c8 = 0; c8 < D_; c8 += 8) {
    u16 tmp[8];
    #pragma unroll
    for (int j = 0; j < 8; j++) tmp[j] = f2b(of[c8 + j] * inv);
    *(uint4*)&op[c8] = *(const uint4*)tmp;
  }
}

// ---------------- persistent LSTM v9 (best: 8.2k cy/step; ladder closed) ----
// Producer: bf16 data stores (agent) -> own-wave vmcnt(0) ack -> per-wave
// sentinel. Consumer: sentinel spin (1KB set) -> payload read EXACTLY once
// with counted vmcnt ladder. Drain-free stamped variants regressed 1.5-2.3x
// (cross-XCD visibility ~3k cy; retries re-read the full wire). v16's fused
// gate-GEMM overlap also regressed. Keep as-is.
#define ISSUE2(K) { \
  const u16* b0_ = hb + ((size_t)(wave * 16 + (K) * 2 + (quad >> 1))) * 512 + \
                   (quad & 1) * 8 + l16 * 16; \
  asm volatile("global_load_dwordx4 %0, %1, off sc0 sc1" : "=v"(ba[K][0]) : "v"(b0_) : "memory"); \
  asm volatile("global_load_dwordx4 %0, %1, off sc0 sc1" : "=v"(ba[K][1]) : "v"(b0_ + 256) : "memory"); }

#define DO_MFMA(A0,A1,KC)                                                           \
  { _Pragma("unroll") for (int g_ = 0; g_ < 3; g_++) {                              \
      s16x8 wf_ = *(const s16x8*)&Wl[wave][((g_ * 8 + (KC)) * 64 + lane) * 8];      \
      acc[g_][0] = __builtin_amdgcn_mfma_f32_16x16x32_bf16(A0, wf_, acc[g_][0], 0, 0, 0); \
      acc[g_][1] = __builtin_amdgcn_mfma_f32_16x16x32_bf16(A1, wf_, acc[g_][1], 0, 0, 0); } \
    acc[3][0] = __builtin_amdgcn_mfma_f32_16x16x32_bf16(A0, wo[KC], acc[3][0], 0, 0, 0);  \
    acc[3][1] = __builtin_amdgcn_mfma_f32_16x16x32_bf16(A1, wo[KC], acc[3][1], 0, 0, 0); }

#define CONSUME(K, NSTR) { \
  asm volatile("s_waitcnt vmcnt(" NSTR ")" ::: "memory"); \
  __builtin_amdgcn_sched_barrier(0); \
  DO_MFMA(ba[K][0], ba[K][1], K); }

__global__ __launch_bounds__(256, 1) void lstm_persistent(
    const u16* __restrict__ g_x, const u16* __restrict__ WhT,
    u16* __restrict__ hb16, u32* __restrict__ sent, float* __restrict__ out)
{
  __shared__ __align__(16) u16 Wl[4][3 * 8 * 64 * 8];  // gates 0-2: 96 KB
  __shared__ float P[4][4][32][17];                     // partials: 34.8 KB
  const int bk = blockIdx.x, tid = threadIdx.x;
  const int wave = tid >> 6, lane = tid & 63;
  const int quad = lane >> 4, l16 = lane & 15;

  // one-time weight staging, directly from WhT (rearranged addressing)
  for (int i = lane; i < 3 * 8 * 64; i += 64) {
    const int g  = (i >> 9) & 3;
    const int kc = (i >> 6) & 7;
    const int row = g * H_ + bk * 16 + (lane & 15);
    const int col = wave * 256 + kc * 32 + (lane >> 4) * 8;
    *(uint4*)&Wl[wave][i * 8] = *(const uint4*)&WhT[(size_t)row * H_ + col];
  }
  s16x8 wo[8];                       // gate-3 weights in registers
  {
    const int row = 3 * H_ + bk * 16 + (lane & 15);
    const int colb = wave * 256 + (lane >> 4) * 8;
    #pragma unroll
    for (int kc = 0; kc < 8; kc++)
      wo[kc] = *(const s16x8*)&WhT[(size_t)row * H_ + colb + kc * 32];
  }
  __syncthreads();

  const int pb = tid >> 4, pc = tid & 15;
  const int col = bk * 16 + pc;
  float creg[2] = {0.0f, 0.0f};

  float gxp[2][4];
  #pragma unroll
  for (int ii = 0; ii < 2; ii++)
    #pragma unroll
    for (int g = 0; g < 4; g++)
      gxp[ii][g] = b2f(g_x[((size_t)(pb + ii * 16)) * (4 * H_) + g * H_ + col]);

  s16x8 ba[8][2];   // all 8 k-banks in flight (64 VGPRs), static indexing

  for (int t = 0; t < T_; t++) {
    if (t > 0) {
      const u32 st = (u32)t;                       // h(t-1) published with value t
      const u16* hb = hb16 + ((t & 1) ^ 1) * 32768;

      // ---- acquire: wait for the 64 producer-wave sentinels this wave needs
      { const u32* sp = sent + ((size_t)(((t & 1) ^ 1) * 256 + wave * 64 + lane));
        u32 sv;
        do {
          asm volatile("global_load_dword %0, %1, off sc0 sc1\n\ts_waitcnt vmcnt(0)"
                       : "=v"(sv) : "v"(sp) : "memory");
        } while (!__all(sv == st)); }

      f32x4 acc[4][2] = {};
      // issue all 16 data loads (read-once), then counted-vmcnt drain + MFMA
      ISSUE2(0) ISSUE2(1) ISSUE2(2) ISSUE2(3)
      ISSUE2(4) ISSUE2(5) ISSUE2(6) ISSUE2(7)
      CONSUME(0, "14") CONSUME(1, "12") CONSUME(2, "10") CONSUME(3, "8")
      CONSUME(4, "6")  CONSUME(5, "4")  CONSUME(6, "2")  CONSUME(7, "0")

      #pragma unroll
      for (int g = 0; g < 4; g++)
        #pragma unroll
        for (int mt = 0; mt < 2; mt++)
          #pragma unroll
          for (int r = 0; r < 4; r++)
            P[wave][g][mt * 16 + quad * 4 + r][l16] = acc[g][mt][r];
    }
    __syncthreads();

    // reduce partials into gate sums (register-only after this)
    float gs[2][4];
    #pragma unroll
    for (int ii = 0; ii < 2; ii++) {
      const int b_ = pb + ii * 16;
      #pragma unroll
      for (int g = 0; g < 4; g++) {
        float s = gxp[ii][g];
        if (t > 0) s += P[0][g][b_][pc] + P[1][g][b_][pc] + P[2][g][b_][pc] + P[3][g][b_][pc];
        gs[ii][g] = s;
      }
    }
    __syncthreads();   // P consumed; next step may overwrite

    // pointwise
    float hn[2], cn[2];
    #pragma unroll
    for (int ii = 0; ii < 2; ii++) {
      const float iv = sigm(gs[ii][0]);
      const float jv = tanh_fast(gs[ii][1]);
      const float fv = sigm(gs[ii][2]);
      const float ov = sigm(gs[ii][3]);
      cn[ii] = fv * creg[ii] + iv * jv;
      hn[ii] = ov * cn[ii];
      creg[ii] = cn[ii];
    }

    // ---- release: bf16 data stores (agent) -> own-wave drain -> sentinel ----
    {
      u32 lo0 = f2b(hn[0]), lo1 = f2b(hn[1]);
      u32 hi0 = __shfl_down(lo0, 1), hi1 = __shfl_down(lo1, 1);
      if ((pc & 1) == 0) {
        u32* hw32 = (u32*)(hb16 + (t & 1) * 32768);
        u32 dw0 = lo0 | (hi0 << 16);
        u32 dw1 = lo1 | (hi1 << 16);
        __hip_atomic_store(&hw32[(size_t)bk * 256 + pb * 8 + (pc >> 1)], dw0,
                           __ATOMIC_RELAXED, __HIP_MEMORY_SCOPE_AGENT);
        __hip_atomic_store(&hw32[(size_t)bk * 256 + (pb + 16) * 8 + (pc >> 1)], dw1,
                           __ATOMIC_RELAXED, __HIP_MEMORY_SCOPE_AGENT);
      }
      asm volatile("s_waitcnt vmcnt(0)" ::: "memory");
      if (lane == 0)
        __hip_atomic_store(&sent[(size_t)(t & 1) * 256 + bk * 4 + wave], (u32)(t + 1),
                           __ATOMIC_RELAXED, __HIP_MEMORY_SCOPE_AGENT);
    }

    // deferred: fp32 outputs + next g_x prefetch (off critical path)
    #pragma unroll
    for (int ii = 0; ii < 2; ii++) {
      const int b_ = pb + ii * 16;
      out[(size_t)t * (B_ * H_) + b_ * H_ + col] = hn[ii];
      if (t == T_ - 1) {
        out[(size_t)T_ * B_ * H_ + b_ * H_ + col] = cn[ii];              // c_f
        out[(size_t)T_ * B_ * H_ + B_ * H_ + b_ * H_ + col] = hn[ii];    // h_f
      }
    }
    if (t < T_ - 1) {
      #pragma unroll
      for (int ii = 0; ii < 2; ii++)
        #pragma unroll
        for (int g = 0; g < 4; g++)
          gxp[ii][g] = b2f(g_x[((size_t)(t + 1) * B_ + pb + ii * 16) * (4 * H_) + g * H_ + col]);
    }
  }
}

extern "C" void kernel_launch(void* const* d_in, const int* in_sizes, int n_in,
                              void* d_out, int out_size, void* d_ws, size_t ws_size,
                              hipStream_t stream)
{
  const float* x        = (const float*)d_in[0];
  const float* src_bias = (const float*)d_in[1];
  const float* mem      = (const float*)d_in[3];
  const float* Wq = (const float*)d_in[4];  const float* bq = (const float*)d_in[5];
  const float* Wk = (const float*)d_in[6];  const float* bk = (const float*)d_in[7];
  const float* Wv = (const float*)d_in[8];  const float* bv = (const float*)d_in[9];
  const float* Wo = (const float*)d_in[10]; const float* bo = (const float*)d_in[11];
  const float* W1 = (const float*)d_in[12]; const float* b1f = (const float*)d_in[13];
  const float* W2 = (const float*)d_in[14]; const float* b2f_ = (const float*)d_in[15];
  const float* Wg = (const float*)d_in[16]; const float* bg = (const float*)d_in[17];
  float* out = (float*)d_out;

  char* p = (char*)d_ws;
  u16* xb   = (u16*)p; p += (size_t)TB_ * H_ * 2;
  u16* memb = (u16*)p; p += (size_t)SB_ * H_ * 2;
  u16* WqT  = (u16*)p; p += (size_t)H_ * H_ * 2;
  u16* WkT  = (u16*)p; p += (size_t)H_ * H_ * 2;
  u16* WvT  = (u16*)p; p += (size_t)H_ * H_ * 2;
  u16* WoT  = (u16*)p; p += (size_t)H_ * H_ * 2;
  u16* W1T  = (u16*)p; p += (size_t)F_ * H_ * 2;
  u16* W2T  = (u16*)p; p += (size_t)H_ * F_ * 2;
  u16* WgxT = (u16*)p; p += (size_t)(4 * H_) * (2 * H_) * 2;
  u16* WhT  = (u16*)p; p += (size_t)(4 * H_) * H_ * 2;
  u16* qb   = (u16*)p; p += (size_t)TB_ * H_ * 2;
  u16* kb   = (u16*)p; p += (size_t)SB_ * H_ * 2;
  u16* vb   = (u16*)p; p += (size_t)SB_ * H_ * 2;
  u16* ctxb = (u16*)p; p += (size_t)TB_ * H_ * 2;
  u16* xs   = (u16*)p; p += (size_t)TB_ * (2 * H_) * 2;
  u16* h1   = (u16*)p; p += (size_t)TB_ * F_ * 2;    // FFN hidden; reused as g_x
  u16* hb16 = (u16*)p; p += (size_t)2 * 32768 * 2;   // raw bf16 h, double-buffered
  u32* sent = (u32*)p; p += (size_t)2 * 256 * 4;     // per-producer-wave sentinels
  u16* gx   = h1;

  // ---- launch 1: prep (sentinel zero + casts + gb1's weight transposes) ----
  prep_all<<<dim3(NB_PREP), dim3(256), 0, stream>>>(
      x, mem, Wq, Wk, Wv, W1, xb, memb, WqT, WkT, WvT, W1T, sent);

  // ---- launch 2: batched GEMMs {q, k, v, ffn1} ----
  GBatch gb1 = {};
  gb1.j[0] = { xb,   WqT, qb, bq,  H_, H_, 0, H_ / 256, (TB_ / 256) * (H_ / 256), 0.125f };
  gb1.j[1] = { memb, WkT, kb, bk,  H_, H_, 0, H_ / 256, (SB_ / 256) * (H_ / 256), 1.0f   };
  gb1.j[2] = { memb, WvT, vb, bv,  H_, H_, 0, H_ / 256, (SB_ / 256) * (H_ / 256), 1.0f   };
  gb1.j[3] = { xb,   W1T, h1, b1f, H_, F_, 1, F_ / 256, (TB_ / 256) * (F_ / 256), 1.0f   };
  gb1.starts[0] = 0;
  gb1.starts[1] = gb1.j[0].nblk;
  gb1.starts[2] = gb1.starts[1] + gb1.j[1].nblk;
  gb1.starts[3] = gb1.starts[2] + gb1.j[2].nblk;
  gb1.njobs = 4;
  const int nb1 = gb1.starts[3] + gb1.j[3].nblk;   // 768
  gemm256<<<dim3(nb1), dim3(512), 0, stream>>>(gb1);

  // ---- launch 3: attention + late-weight transposes in its shadow ----
  attn_prep<<<dim3(NB_ATTNL), dim3(256), 0, stream>>>(
      qb, kb, vb, src_bias, ctxb, Wo, W2, Wg, WoT, W2T, WgxT, WhT);

  // ---- launch 4: batched GEMMs {o-proj, ffn2} ----
  GBatch gb2 = {};
  gb2.j[0] = { ctxb, WoT, xs + H_, bo,   H_, 2 * H_, 0, H_ / 256, (TB_ / 256) * (H_ / 256), 1.0f };
  gb2.j[1] = { h1,   W2T, xs,      b2f_, F_, 2 * H_, 0, H_ / 256, (TB_ / 256) * (H_ / 256), 1.0f };
  gb2.starts[0] = 0;
  gb2.starts[1] = gb2.j[0].nblk;
  gb2.njobs = 2;
  const int nb2 = gb2.starts[1] + gb2.j[1].nblk;   // 256
  gemm256<<<dim3(nb2), dim3(512), 0, stream>>>(gb2);

  // ---- launch 5: gate x-part GEMM ----
  GBatch gb3 = {};
  gb3.j[0] = { xs, WgxT, gx, bg, 2 * H_, 4 * H_, 0, 4 * H_ / 256, (TB_ / 256) * (4 * H_ / 256), 1.0f };
  gb3.starts[0] = 0;
  gb3.njobs = 1;
  gemm256<<<dim3(gb3.j[0].nblk), dim3(512), 0, stream>>>(gb3);   // 512

  // ---- launch 6: persistent LSTM (v9 sync structure) ----
  lstm_persistent<<<dim3(64), dim3(256), 0, stream>>>(gx, WhT, hb16, sent, out);
}